// Round 7
// baseline (444.353 us; speedup 1.0000x reference)
//
#include <hip/hip_runtime.h>

#define D 128
#define LSTR 132   // padded LDS row stride (floats)
#define CAP 3072   // LDS edge capacity per 32-row tile (avg ~512)
#define NBLK 256   // fixed hist/fill block count (G columns)
#define NSL 8      // channel slices (== XCD count; 16 ch x 2B = 32B each)

typedef __attribute__((ext_vector_type(8))) short short8;
typedef __attribute__((ext_vector_type(4))) float f32x4;

static __device__ __forceinline__ unsigned short f2bf(float f) {
    unsigned u = __float_as_uint(f);
    return (unsigned short)((u + 0x7fffu + ((u >> 16) & 1u)) >> 16);  // RNE
}
static __device__ __forceinline__ float b2f(unsigned short u) {
    return __uint_as_float(((unsigned)u) << 16);
}

// ---------------------------------------------------------------------------
// GraphSAGE (mean) x2 + head. bf16 features (fp32 accumulate).
// Features stored SLICE-MAJOR: xbS[s][node][16ch] -> each slice = contiguous
// 1.6MB (fits one XCD's 4MB L2).
// Prep = R0 proven chain (LDS-sort): prep+histA, scanB, scanC, fillB, sortT.
// Layer 1 split for XCD-local gather:
//   sageA: grid nbins*8; block (tile b, slice s=bid&7). Round-robin dispatch
//     puts slice s on XCD s -> gather working set = resident 1.6MB slice.
//     Lane-pairs own CONTIGUOUS edge runs (register seg-accumulate), 32B/edge.
//     csr via nontemporal loads, agg partial via nontemporal stores (no L2
//     pollution of the slice). -> agg[node][128] fp32.
//   sageB: per-tile MFMA dual GEMM from agg (mean via invL) + self term.
// Layer 2 = R0-style monolithic sage (slice-major addressing) + HEAD
//   -> same-run A/B control vs sliced layer 1.
// d_ws: tot[2048] | tile_base[2052] | invL_g[Npad] | G[2048*NBLK] | csr[Epad]
//       | agg f32[Npad*128] | xbS bf16[N*D] | hbS bf16[N*D] | Bt1 | Bt2
// ---------------------------------------------------------------------------

// Blocks [0, NBLK): LDS histogram of dst tiles. Blocks [NBLK, ...): prep.
__global__ __launch_bounds__(256) void prep_hist_kernel(
    const float* __restrict__ x, const float* __restrict__ W1l,
    const float* __restrict__ W1r, const float* __restrict__ W2l,
    const float* __restrict__ W2r, unsigned short* __restrict__ xbS,
    unsigned short* __restrict__ Bt1, unsigned short* __restrict__ Bt2,
    int NC, int N, const int* __restrict__ dst, int E, int nbins,
    unsigned* __restrict__ G) {
    const int t = threadIdx.x;
    if (blockIdx.x < NBLK) {
        __shared__ int h[2048];
        for (int i = t; i < nbins; i += 256) h[i] = 0;
        __syncthreads();
        const int per = (E + NBLK - 1) / NBLK;
        const int lo = blockIdx.x * per;
        const int hi = min(lo + per, E);
        for (int i = lo + t; i < hi; i += 256) atomicAdd(&h[dst[i] >> 5], 1);
        __syncthreads();
        for (int i = t; i < nbins; i += 256)
            G[(size_t)i * NBLK + blockIdx.x] = (unsigned)h[i];
        return;
    }
    const int i = (blockIdx.x - NBLK) * 256 + t;
    if (i < NC) {
        const int s = i / N;  // slice 0..7
        const int v = i - s * N;
        const float* xp = x + (size_t)v * 128 + s * 16;
        const float4 f0 = *(const float4*)(xp + 0);
        const float4 f1 = *(const float4*)(xp + 4);
        const float4 f2 = *(const float4*)(xp + 8);
        const float4 f3 = *(const float4*)(xp + 12);
        uint4 lo, hi;
        lo.x = (unsigned)f2bf(f0.x) | ((unsigned)f2bf(f0.y) << 16);
        lo.y = (unsigned)f2bf(f0.z) | ((unsigned)f2bf(f0.w) << 16);
        lo.z = (unsigned)f2bf(f1.x) | ((unsigned)f2bf(f1.y) << 16);
        lo.w = (unsigned)f2bf(f1.z) | ((unsigned)f2bf(f1.w) << 16);
        hi.x = (unsigned)f2bf(f2.x) | ((unsigned)f2bf(f2.y) << 16);
        hi.y = (unsigned)f2bf(f2.z) | ((unsigned)f2bf(f2.w) << 16);
        hi.z = (unsigned)f2bf(f3.x) | ((unsigned)f2bf(f3.y) << 16);
        hi.w = (unsigned)f2bf(f3.z) | ((unsigned)f2bf(f3.w) << 16);
        unsigned short* op = xbS + ((size_t)s * N + v) * 16;
        *(uint4*)op = lo;
        *(uint4*)(op + 8) = hi;
    } else if (i < NC + 2 * 32768) {
        const int j = i - NC;
        const int which = j >> 15;  // 0 -> layer1, 1 -> layer2
        const int jj = j & 32767;
        const int n = jj >> 8;
        const int k = jj & 255;
        const float* Wl = which ? W2l : W1l;
        const float* Wr = which ? W2r : W1r;
        const float w = (k < 128) ? Wl[k * 128 + n] : Wr[(k - 128) * 128 + n];
        (which ? Bt2 : Bt1)[jj] = f2bf(w);
    }
}

// One wave per bin: coalesced uint4 exclusive scan over the 256 columns.
__global__ __launch_bounds__(256) void scanB_kernel(unsigned* __restrict__ G,
                                                    int nbins,
                                                    int* __restrict__ tot) {
    const int wave = threadIdx.x >> 6;
    const int lane = threadIdx.x & 63;
    const int bin = blockIdx.x * 4 + wave;
    if (bin >= nbins) return;
    unsigned* p = G + (size_t)bin * NBLK + lane * 4;
    uint4 v = *(uint4*)p;
    const unsigned s = v.x + v.y + v.z + v.w;
    unsigned sc = s;
#pragma unroll
    for (int off = 1; off < 64; off <<= 1) {
        const unsigned u = (unsigned)__shfl_up((int)sc, off, 64);
        if (lane >= off) sc += u;
    }
    const unsigned excl = sc - s;
    uint4 w;
    w.x = excl;
    w.y = excl + v.x;
    w.z = excl + v.x + v.y;
    w.w = excl + v.x + v.y + v.z;
    *(uint4*)p = w;
    if (lane == 63) tot[bin] = (int)(excl + s);
}

// Single-block exclusive scan of tot -> tile_base[0..nbins].
__global__ __launch_bounds__(1024) void scanC_kernel(
    const int* __restrict__ tot, int nbins, int* __restrict__ tile_base) {
    __shared__ int part[1024];
    const int t = threadIdx.x;
    const int chunk = (nbins + 1023) >> 10;
    const int lo = min(t * chunk, nbins);
    const int hi = min(lo + chunk, nbins);
    int s = 0;
    for (int i = lo; i < hi; ++i) s += tot[i];
    part[t] = s;
    __syncthreads();
    for (int off = 1; off < 1024; off <<= 1) {
        int add = (t >= off) ? part[t - off] : 0;
        __syncthreads();
        part[t] += add;
        __syncthreads();
    }
    int excl = (t == 0) ? 0 : part[t - 1];
    for (int i = lo; i < hi; ++i) {
        tile_base[i] = excl;
        excl += tot[i];
    }
    if (t == 1023) tile_base[nbins] = part[1023];
}

// Rank replay + scatter into tile-grouped csr.
__global__ __launch_bounds__(256) void fillB_kernel(
    const int* __restrict__ src, const int* __restrict__ dst, int E,
    const unsigned* __restrict__ G, const int* __restrict__ tile_base,
    unsigned* __restrict__ csr, int nbins) {
    __shared__ int rank[2048];
    __shared__ int base[2048];
    const int t = threadIdx.x;
    for (int i = t; i < nbins; i += 256) {
        rank[i] = 0;
        base[i] = tile_base[i] + (int)G[(size_t)i * NBLK + blockIdx.x];
    }
    __syncthreads();
    const int per = (E + NBLK - 1) / NBLK;
    const int lo = blockIdx.x * per;
    const int hi = min(lo + per, E);
    for (int i = lo + t; i < hi; i += 256) {
        const int d = dst[i];
        const int bin = d >> 5;
        const int r = atomicAdd(&rank[bin], 1);
        csr[base[bin] + r] = (unsigned)src[i] | ((unsigned)d << 16);
    }
}

// One block per tile: in-LDS 32-bin counting sort (row-grouped, in place)
// + invL_g = 1/max(deg,1). Runs once, reused by both layers.
__global__ __launch_bounds__(256) void sortT_kernel(unsigned* __restrict__ csr,
                                                    const int* __restrict__
                                                        tile_base,
                                                    float* __restrict__ invL_g,
                                                    int N) {
    __shared__ unsigned sortedE[CAP];
    __shared__ int rowcnt[32];
    __shared__ int rowofs[32];
    const int b = blockIdx.x;
    const int i0 = b * 32;
    const int t = threadIdx.x;
    const int rs0 = tile_base[b];
    const int re0 = tile_base[b + 1];
    const int nE = re0 - rs0;

    if (t < 32) rowcnt[t] = 0;
    __syncthreads();
    for (int i = t; i < nE; i += 256)
        atomicAdd(&rowcnt[(csr[rs0 + i] >> 16) & 31], 1);
    __syncthreads();
    if (t < 32) {
        const int v = rowcnt[t];
        if (i0 + t < N) invL_g[i0 + t] = 1.0f / fmaxf((float)v, 1.0f);
        int s = v;
#pragma unroll
        for (int off = 1; off < 32; off <<= 1) {
            const int u = __shfl_up(s, off, 32);
            if ((t & 31) >= off) s += u;
        }
        rowofs[t] = s - v;
    }
    __syncthreads();
    if (nE <= CAP) {
        for (int i = t; i < nE; i += 256) {
            const unsigned p = csr[rs0 + i];
            const int k = atomicAdd(&rowofs[(p >> 16) & 31], 1);
            sortedE[k] = p;
        }
        __syncthreads();
        for (int i = t; i < nE; i += 256) csr[rs0 + i] = sortedE[i];
    }
}

// Layer-1 gather, XCD-sliced: block (tile b, slice s = bid&7). Each lane
// pair owns a CONTIGUOUS edge run; 32B/edge gathered from the slice.
__global__ __launch_bounds__(256) void sageA_kernel(
    const unsigned short* __restrict__ xbS, const unsigned* __restrict__ csr,
    const int* __restrict__ tile_base, float* __restrict__ agg, int N) {
    __shared__ float aggS[32][16];
    const int bid = blockIdx.x;
    const int s = bid & 7;
    const int b = bid >> 3;
    const int i0 = b * 32;
    const int t = threadIdx.x;

    if (t < 128) ((f32x4*)&aggS[0][0])[t] = f32x4{0.f, 0.f, 0.f, 0.f};
    __syncthreads();

    const int rs0 = tile_base[b];
    const int re0 = tile_base[b + 1];
    const int nE = re0 - rs0;
    const int wv = t >> 6;
    const int lane = t & 63;
    const int k = lane >> 1;  // pair index 0..31
    const int h = lane & 1;   // half of the 32B slice chunk
    const int we0 = rs0 + ((nE * wv) >> 2);
    const int wcnt = (rs0 + ((nE * (wv + 1)) >> 2)) - we0;
    int e = we0 + ((wcnt * k) >> 5);
    const int pe = we0 + ((wcnt * (k + 1)) >> 5);

    const unsigned short* base = xbS + (size_t)s * N * 16 + h * 8;

    float a[8];
#pragma unroll
    for (int m = 0; m < 8; ++m) a[m] = 0.f;
    int cur = -1;

    auto ld = [&](unsigned p) -> uint4 {
        return *(const uint4*)(base + (size_t)(p & 0xffffu) * 16);
    };
    auto flush = [&]() {
        float* q = &aggS[cur][h * 8];
#pragma unroll
        for (int m = 0; m < 8; ++m) atomicAdd(q + m, a[m]);
    };
    auto step = [&](unsigned p, const uint4& u) {
        const int r = (int)(p >> 16) - i0;
        if (r != cur) {
            if (cur >= 0) flush();
#pragma unroll
            for (int m = 0; m < 8; ++m) a[m] = 0.f;
            cur = r;
        }
        a[0] += __uint_as_float(u.x << 16);
        a[1] += __uint_as_float(u.x & 0xffff0000u);
        a[2] += __uint_as_float(u.y << 16);
        a[3] += __uint_as_float(u.y & 0xffff0000u);
        a[4] += __uint_as_float(u.z << 16);
        a[5] += __uint_as_float(u.z & 0xffff0000u);
        a[6] += __uint_as_float(u.w << 16);
        a[7] += __uint_as_float(u.w & 0xffff0000u);
    };

    while (e + 4 <= pe) {
        const unsigned p0 = __builtin_nontemporal_load(csr + e + 0);
        const unsigned p1 = __builtin_nontemporal_load(csr + e + 1);
        const unsigned p2 = __builtin_nontemporal_load(csr + e + 2);
        const unsigned p3 = __builtin_nontemporal_load(csr + e + 3);
        const uint4 u0 = ld(p0), u1 = ld(p1), u2 = ld(p2), u3 = ld(p3);
        step(p0, u0);
        step(p1, u1);
        step(p2, u2);
        step(p3, u3);
        e += 4;
    }
    while (e < pe) {
        const unsigned p = __builtin_nontemporal_load(csr + e);
        step(p, ld(p));
        ++e;
    }
    if (cur >= 0) flush();
    __syncthreads();

    // write partial agg (owned exclusively by this block): NT, no L2 pollute
    const int row = t >> 3;
    const int c2 = (t & 7) * 2;
    float* dp = agg + (size_t)(i0 + row) * 128 + s * 16 + c2;
    __builtin_nontemporal_store(aggS[row][c2], dp);
    __builtin_nontemporal_store(aggS[row][c2 + 1], dp + 1);
}

// Layer-1 MFMA: dual GEMM from agg (mean via invL) + self term, -> hbS.
__global__ __launch_bounds__(256) void sageB_kernel(
    const float* __restrict__ agg, const unsigned short* __restrict__ xbS,
    const float* __restrict__ invL_g, const unsigned short* __restrict__ Bt,
    const float* __restrict__ bl, unsigned short* __restrict__ hbS, int N) {
    const int b = blockIdx.x;
    const int i0 = b * 32;
    const int t = threadIdx.x;
    const int wave = t >> 6;
    const int lane = t & 63;
    const int ln = lane & 15;
    const int quad = lane >> 4;
    const int mtile = wave & 1;
    const int nt0 = (wave >> 1) * 4;
    const int mrow = mtile * 16 + ln;
    const int gmr = i0 + mrow;
    const float inv = (gmr < N) ? invL_g[gmr] : 1.0f;

    f32x4 acc4[4] = {f32x4{0.f, 0.f, 0.f, 0.f}, f32x4{0.f, 0.f, 0.f, 0.f},
                     f32x4{0.f, 0.f, 0.f, 0.f}, f32x4{0.f, 0.f, 0.f, 0.f}};

#pragma unroll
    for (int s4 = 0; s4 < 4; ++s4) {
        const int kb = s4 * 32 + quad * 8;
        const float* ap = agg + (size_t)gmr * 128 + kb;
        const float4 fa = *(const float4*)ap;
        const float4 fb = *(const float4*)(ap + 4);
        const short8 aA = {(short)f2bf(fa.x * inv), (short)f2bf(fa.y * inv),
                           (short)f2bf(fa.z * inv), (short)f2bf(fa.w * inv),
                           (short)f2bf(fb.x * inv), (short)f2bf(fb.y * inv),
                           (short)f2bf(fb.z * inv), (short)f2bf(fb.w * inv)};
        short8 aX = {0, 0, 0, 0, 0, 0, 0, 0};
        if (gmr < N)
            aX = *(const short8*)(xbS + ((size_t)(kb >> 4) * N + gmr) * 16 +
                                  (kb & 15));
#pragma unroll
        for (int nt = 0; nt < 4; ++nt) {
            const int n = (nt0 + nt) * 16 + ln;
            const short8 b1 = *(const short8*)(Bt + n * 256 + kb);
            const short8 b2 = *(const short8*)(Bt + n * 256 + 128 + kb);
            acc4[nt] = __builtin_amdgcn_mfma_f32_16x16x32_bf16(aA, b1, acc4[nt],
                                                               0, 0, 0);
            acc4[nt] = __builtin_amdgcn_mfma_f32_16x16x32_bf16(aX, b2, acc4[nt],
                                                               0, 0, 0);
        }
    }

    float biasv[4];
#pragma unroll
    for (int nt = 0; nt < 4; ++nt) biasv[nt] = bl[(nt0 + nt) * 16 + ln];

#pragma unroll
    for (int r = 0; r < 4; ++r) {
        const int gr = i0 + mtile * 16 + quad * 4 + r;
        if (gr < N) {
#pragma unroll
            for (int nt = 0; nt < 4; ++nt) {
                const float v = fmaxf(acc4[nt][r] + biasv[nt], 0.f);
                hbS[((size_t)(nt0 + nt) * N + gr) * 16 + ln] = f2bf(v);
            }
        }
    }
}

// Layer-2 (A/B control): R0-style monolithic sage on slice-major hbS + HEAD.
template <bool HEAD>
__global__ __launch_bounds__(256) void sage_kernel(
    const unsigned short* __restrict__ xb, const unsigned* __restrict__ csr,
    const int* __restrict__ tile_base, const float* __restrict__ invL_g,
    const unsigned short* __restrict__ Bt,  // [128 n][256 k] bf16
    const float* __restrict__ bl, const float* __restrict__ Wout,
    const float* __restrict__ bout, unsigned short* __restrict__ hb_out,
    float* __restrict__ out, int N) {
    __shared__ float aggL[32 * LSTR];
    __shared__ float invL[32];
    __shared__ float redH[64];

    const int b = blockIdx.x;
    const int i0 = b * 32;
    const int t = threadIdx.x;
    const int g = t >> 5;
    const int l = t & 31;
    const int c4 = l << 2;

    for (int i = t; i < 32 * LSTR; i += 256) aggL[i] = 0.f;
    if (t < 32) invL[t] = (i0 + t < N) ? invL_g[i0 + t] : 1.0f;
    __syncthreads();

    // ---- segmented edge-parallel aggregation over row-sorted csr ----
    const int rs0 = tile_base[b];
    const int re0 = tile_base[b + 1];
    const int nE = re0 - rs0;
    int e = rs0 + ((nE * g) >> 3);
    const int ee = rs0 + ((nE * (g + 1)) >> 3);

    // slice-major address of this lane's 4 channels
    const unsigned short* gbase = xb + (size_t)(l >> 2) * N * 16 + (l & 3) * 4;

    float4 acc = make_float4(0.f, 0.f, 0.f, 0.f);
    int cur = (e < ee) ? (int)(csr[e] >> 16) - i0 : -1;

    auto load4 = [&](unsigned p) -> float4 {
        const ushort4 u = *(const ushort4*)(gbase + (size_t)(p & 0xffffu) * 16);
        float4 v;
        v.x = b2f(u.x); v.y = b2f(u.y); v.z = b2f(u.z); v.w = b2f(u.w);
        return v;
    };
    auto step = [&](unsigned p, const float4& v) {
        const int r = (int)(p >> 16) - i0;
        if (r != cur) {
            float* q = aggL + cur * LSTR + c4;
            atomicAdd(q + 0, acc.x);
            atomicAdd(q + 1, acc.y);
            atomicAdd(q + 2, acc.z);
            atomicAdd(q + 3, acc.w);
            acc = make_float4(0.f, 0.f, 0.f, 0.f);
            cur = r;
        }
        acc.x += v.x; acc.y += v.y; acc.z += v.z; acc.w += v.w;
    };

    while (e + 8 <= ee) {
        const unsigned p0 = csr[e + 0], p1 = csr[e + 1];
        const unsigned p2 = csr[e + 2], p3 = csr[e + 3];
        const unsigned p4 = csr[e + 4], p5 = csr[e + 5];
        const unsigned p6 = csr[e + 6], p7 = csr[e + 7];
        const float4 v0 = load4(p0), v1 = load4(p1), v2 = load4(p2),
                     v3 = load4(p3), v4 = load4(p4), v5 = load4(p5),
                     v6 = load4(p6), v7 = load4(p7);
        step(p0, v0); step(p1, v1); step(p2, v2); step(p3, v3);
        step(p4, v4); step(p5, v5); step(p6, v6); step(p7, v7);
        e += 8;
    }
    while (e < ee) {
        const unsigned p = csr[e];
        step(p, load4(p));
        ++e;
    }
    if (cur >= 0) {
        float* q = aggL + cur * LSTR + c4;
        atomicAdd(q + 0, acc.x);
        atomicAdd(q + 1, acc.y);
        atomicAdd(q + 2, acc.z);
        atomicAdd(q + 3, acc.w);
    }
    __syncthreads();

    // ---- MFMA dual GEMM: [agg*inv | x](32x256) @ Bt^T(256x128) ----
    const int wave = t >> 6;
    const int lane = t & 63;
    const int ln = lane & 15;
    const int quad = lane >> 4;
    const int mtile = wave & 1;
    const int nt0 = (wave >> 1) * 4;
    const int mrow = mtile * 16 + ln;
    const int gmr = i0 + mrow;
    const float inv = invL[mrow];

    f32x4 acc4[4] = {f32x4{0.f, 0.f, 0.f, 0.f}, f32x4{0.f, 0.f, 0.f, 0.f},
                     f32x4{0.f, 0.f, 0.f, 0.f}, f32x4{0.f, 0.f, 0.f, 0.f}};

#pragma unroll
    for (int s4 = 0; s4 < 4; ++s4) {
        const int kb = s4 * 32 + quad * 8;
        const float* ap = aggL + mrow * LSTR + kb;
        const float4 fa = *(const float4*)ap;
        const float4 fb = *(const float4*)(ap + 4);
        const short8 aA = {(short)f2bf(fa.x * inv), (short)f2bf(fa.y * inv),
                           (short)f2bf(fa.z * inv), (short)f2bf(fa.w * inv),
                           (short)f2bf(fb.x * inv), (short)f2bf(fb.y * inv),
                           (short)f2bf(fb.z * inv), (short)f2bf(fb.w * inv)};
        short8 aX = {0, 0, 0, 0, 0, 0, 0, 0};
        if (gmr < N)
            aX = *(const short8*)(xb + ((size_t)(kb >> 4) * N + gmr) * 16 +
                                  (kb & 15));
#pragma unroll
        for (int nt = 0; nt < 4; ++nt) {
            const int n = (nt0 + nt) * 16 + ln;
            const short8 b1 = *(const short8*)(Bt + n * 256 + kb);
            const short8 b2 = *(const short8*)(Bt + n * 256 + 128 + kb);
            acc4[nt] = __builtin_amdgcn_mfma_f32_16x16x32_bf16(aA, b1, acc4[nt],
                                                               0, 0, 0);
            acc4[nt] = __builtin_amdgcn_mfma_f32_16x16x32_bf16(aX, b2, acc4[nt],
                                                               0, 0, 0);
        }
    }

    float biasv[4], woutv[4];
#pragma unroll
    for (int nt = 0; nt < 4; ++nt) {
        const int col = (nt0 + nt) * 16 + ln;
        biasv[nt] = bl[col];
        if (HEAD) woutv[nt] = Wout[col];
    }

    if (!HEAD) {
#pragma unroll
        for (int r = 0; r < 4; ++r) {
            const int gr = i0 + mtile * 16 + quad * 4 + r;
            if (gr < N) {
#pragma unroll
                for (int nt = 0; nt < 4; ++nt) {
                    const float v = fmaxf(acc4[nt][r] + biasv[nt], 0.f);
                    hb_out[((size_t)(nt0 + nt) * N + gr) * 16 + ln] = f2bf(v);
                }
            }
        }
    } else {
        const float b0 = bout[0];
#pragma unroll
        for (int r = 0; r < 4; ++r) {
            const int row = mtile * 16 + quad * 4 + r;
            float p = 0.f;
#pragma unroll
            for (int nt = 0; nt < 4; ++nt) {
                const float v = fmaxf(acc4[nt][r] + biasv[nt], 0.f);
                p += v * woutv[nt];
            }
            p += __shfl_xor(p, 1);
            p += __shfl_xor(p, 2);
            p += __shfl_xor(p, 4);
            p += __shfl_xor(p, 8);
            if (ln == 0) redH[row * 2 + (wave >> 1)] = p;
        }
        __syncthreads();
        if (t < 32) {
            const int gr = i0 + t;
            if (gr < N) out[gr] = redH[t * 2] + redH[t * 2 + 1] + b0;
        }
    }
}

extern "C" void kernel_launch(void* const* d_in, const int* in_sizes, int n_in,
                              void* d_out, int out_size, void* d_ws,
                              size_t ws_size, hipStream_t stream) {
    const float* x = (const float*)d_in[0];
    const int* ei = (const int*)d_in[1];
    const float* W1l = (const float*)d_in[2];
    const float* b1l = (const float*)d_in[3];
    const float* W1r = (const float*)d_in[4];
    const float* W2l = (const float*)d_in[5];
    const float* b2l = (const float*)d_in[6];
    const float* W2r = (const float*)d_in[7];
    const float* Wout = (const float*)d_in[8];
    const float* bout = (const float*)d_in[9];

    const int N = in_sizes[0] / D;
    const int E = in_sizes[1] / 2;
    const int* src = ei;
    const int* dst = ei + E;

    const int nbins = (N + 31) / 32;  // 32-row tiles, <= 2048
    const size_t Npad = (size_t)((N + 255) & ~255);
    const size_t Epad = (size_t)((E + 255) & ~255);

    int* tot = (int*)d_ws;                        // [2048]
    int* tile_base = tot + 2048;                  // [2052]
    float* invL_g = (float*)(tile_base + 2052);   // [Npad]
    unsigned* G = (unsigned*)(invL_g + Npad);     // [2048 * NBLK]
    unsigned* csr = G + (size_t)2048 * NBLK;      // [Epad]
    float* agg = (float*)(csr + Epad);            // [Npad * 128]
    unsigned short* xbS = (unsigned short*)(agg + Npad * 128);
    unsigned short* hbS = xbS + (size_t)N * D;
    unsigned short* Bt1 = hbS + (size_t)N * D;
    unsigned short* Bt2 = Bt1 + 128 * 256;
    float* out = (float*)d_out;

    const int NC = N * NSL;  // cast chunks (node, slice)
    const int prep_blocks = (NC + 2 * 32768 + 255) / 256;

    prep_hist_kernel<<<NBLK + prep_blocks, 256, 0, stream>>>(
        x, W1l, W1r, W2l, W2r, xbS, Bt1, Bt2, NC, N, dst, E, nbins, G);
    scanB_kernel<<<(nbins + 3) / 4, 256, 0, stream>>>(G, nbins, tot);
    scanC_kernel<<<1, 1024, 0, stream>>>(tot, nbins, tile_base);
    fillB_kernel<<<NBLK, 256, 0, stream>>>(src, dst, E, G, tile_base, csr,
                                           nbins);
    sortT_kernel<<<nbins, 256, 0, stream>>>(csr, tile_base, invL_g, N);

    sageA_kernel<<<nbins * NSL, 256, 0, stream>>>(xbS, csr, tile_base, agg, N);
    sageB_kernel<<<nbins, 256, 0, stream>>>(agg, xbS, invL_g, Bt1, b1l, hbS, N);
    sage_kernel<true><<<nbins, 256, 0, stream>>>(
        hbS, csr, tile_base, invL_g, Bt2, b2l, Wout, bout, nullptr, out, N);
}